// Round 1
// baseline (86.675 us; speedup 1.0000x reference)
//
#include <hip/hip_runtime.h>

// out[i] = sum_k a[k] * tanh(5*(x[i]+b[k])), k=0..6
// tanh(z) = 1 - 2/(exp(2z)+1); exp(2*5*(x+b)) = exp2(SC*x + SC*b), SC = 10*log2(e).
// Fused: out = suma + sum_k (-2*a[k]) * rcp(exp2(SC*x + SC*b[k]) + 1)
// Saturation is handled naturally: exp2->inf => rcp->0 => tanh=+1; exp2->0 => rcp->1 => tanh=-1.

#define K_TERMS 7

__device__ __forceinline__ float fast_exp2(float x) { return __builtin_amdgcn_exp2f(x); }
__device__ __forceinline__ float fast_rcp(float x)  { return __builtin_amdgcn_rcpf(x); }

__global__ __launch_bounds__(256)
void quantizationLayer_49563922596433_kernel(const float* __restrict__ x,
                                             const float* __restrict__ w,
                                             float* __restrict__ out,
                                             int n4) {
    const float SC = 14.4269504088896f; // 10 * log2(e)

    // Weights are wave-uniform loads -> compiler lifts to scalar loads/SGPRs.
    float suma = 0.f;
    float cb[K_TERMS], na2[K_TERMS];
#pragma unroll
    for (int k = 0; k < K_TERMS; ++k) {
        float a = w[2 * k + 0];
        float b = w[2 * k + 1];
        suma  += a;
        cb[k]  = SC * b;
        na2[k] = -2.f * a;
    }

    int i = blockIdx.x * blockDim.x + threadIdx.x;
    if (i >= n4) return;

    float4 v = ((const float4*)x)[i];
    float in[4] = {v.x, v.y, v.z, v.w};
    float o[4];
#pragma unroll
    for (int j = 0; j < 4; ++j) {
        float xs  = in[j] * SC;
        float acc = suma;
#pragma unroll
        for (int k = 0; k < K_TERMS; ++k) {
            float e  = fast_exp2(xs + cb[k]);
            float rc = fast_rcp(e + 1.f);
            acc = fmaf(na2[k], rc, acc);
        }
        o[j] = acc;
    }
    float4 ov = {o[0], o[1], o[2], o[3]};
    ((float4*)out)[i] = ov;
}

extern "C" void kernel_launch(void* const* d_in, const int* in_sizes, int n_in,
                              void* d_out, int out_size, void* d_ws, size_t ws_size,
                              hipStream_t stream) {
    const float* x = (const float*)d_in[0];
    const float* w = (const float*)d_in[1];
    float* out = (float*)d_out;

    int n  = in_sizes[0];      // 2048*4096 = 8388608, divisible by 4
    int n4 = n / 4;
    int block = 256;
    int grid = (n4 + block - 1) / block;  // 8192 blocks
    quantizationLayer_49563922596433_kernel<<<grid, block, 0, stream>>>(x, w, out, n4);
}

// Round 2
// 82.404 us; speedup vs baseline: 1.0518x; 1.0518x over previous
//
#include <hip/hip_runtime.h>

// out[i] = sum_k a[k] * tanh(5*(x[i]+b[k])), k=0..6
// tanh(z) = 1 - 2/(exp(2z)+1)
// exp(10*(x+b_k)) = exp2(SC*x) * exp2(SC*b_k) = E * c_k,  SC = 10*log2(e)
// => out = suma + sum_k (-2*a_k) * rcp(E*c_k + 1)
// ONE exp2 per element (shared across all 7 terms) + 7 rcp.
// Range: |SC*x| <= ~80 for |x|<=5.5, c_k in [2^-3.9, 2^3.9] -> E*c_k within f32
// normal range; saturation falls out of rcp(inf)=0 / rcp(~1)=~1 naturally.

#define K_TERMS 7

__device__ __forceinline__ float fast_exp2(float x) { return __builtin_amdgcn_exp2f(x); }
__device__ __forceinline__ float fast_rcp(float x)  { return __builtin_amdgcn_rcpf(x); }

__global__ __launch_bounds__(256)
void quantizationLayer_49563922596433_kernel(const float* __restrict__ x,
                                             const float* __restrict__ w,
                                             float* __restrict__ out,
                                             int n4) {
    const float SC = 14.4269504088896f; // 10 * log2(e)

    // Uniform-address loads -> s_load; all weight-derived constants live in SGPRs.
    float suma = 0.f;
    float ck[K_TERMS], na2[K_TERMS];
#pragma unroll
    for (int k = 0; k < K_TERMS; ++k) {
        float a = w[2 * k + 0];
        float b = w[2 * k + 1];
        suma  += a;
        ck[k]  = fast_exp2(SC * b);   // exp2 of uniform value
        na2[k] = -2.f * a;
    }

    int i = blockIdx.x * blockDim.x + threadIdx.x;
    if (i >= n4) return;

    float4 v = ((const float4*)x)[i];
    float in[4] = {v.x, v.y, v.z, v.w};
    float o[4];
#pragma unroll
    for (int j = 0; j < 4; ++j) {
        float E   = fast_exp2(in[j] * SC);   // one exp2 per element
        float acc = suma;
#pragma unroll
        for (int k = 0; k < K_TERMS; ++k) {
            float d  = fmaf(E, ck[k], 1.f);  // E*c_k + 1
            acc = fmaf(na2[k], fast_rcp(d), acc);
        }
        o[j] = acc;
    }
    float4 ov = {o[0], o[1], o[2], o[3]};
    ((float4*)out)[i] = ov;
}

extern "C" void kernel_launch(void* const* d_in, const int* in_sizes, int n_in,
                              void* d_out, int out_size, void* d_ws, size_t ws_size,
                              hipStream_t stream) {
    const float* x = (const float*)d_in[0];
    const float* w = (const float*)d_in[1];
    float* out = (float*)d_out;

    int n  = in_sizes[0];      // 2048*4096 = 8388608, divisible by 4
    int n4 = n / 4;
    int block = 256;
    int grid = (n4 + block - 1) / block;  // 8192 blocks
    quantizationLayer_49563922596433_kernel<<<grid, block, 0, stream>>>(x, w, out, n4);
}